// Round 23
// baseline (473.172 us; speedup 1.0000x reference)
//
#include <hip/hip_runtime.h>

typedef float f16v __attribute__((ext_vector_type(16)));
typedef float f4 __attribute__((ext_vector_type(4)));
typedef float f2 __attribute__((ext_vector_type(2)));

// static_for with FRONTEND-constant indices (SSA, no alloca) — see R6 notes.
// R20 lesson: inline-asm referencing locals must be at FUNCTION SCOPE (not in lambdas).
template<int I> struct ic { static constexpr int v = I; };
template<int... I> struct iseq {};
template<int N, int... I> struct mk : mk<N-1, N-1, I...> {};
template<int... I> struct mk<0, I...> { using t = iseq<I...>; };
template<class F, int... I>
__device__ __forceinline__ void sfor_impl(F f, iseq<I...>) { (f(ic<I>{}), ...); }
template<int N, class F>
__device__ __forceinline__ void sfor(F f) { sfor_impl(f, typename mk<N>::t{}); }

namespace {
constexpr float kSigma  = 1.2f;    // 2*l2_reg + rho
constexpr float kJitter = 1e-5f;
constexpr int   kIters  = 100;
constexpr int   MD = 16;
constexpr int   ND = 32;
constexpr int   SPA = 8;     // samples per 128-thread block (16 lanes each)
constexpr int   AS  = 132;   // A sample stride in float4
}

__device__ __forceinline__ float4 lds_a4(const float* As, int r, int j) {
    return *reinterpret_cast<const float4*>(&As[r * 32 + ((j ^ (r & 7)) << 2)]);
}
__device__ __forceinline__ f2 lds_a2(const float* As, int r, int n) {
    return *reinterpret_cast<const f2*>(
        &As[r * 32 + ((((n >> 2) ^ (r & 7)) << 2) | (n & 3))]);
}

// ====== Fused: phase1 precompute (R19-proven) + phase2 LDS-exchange, full-rate FMA ======
// R22 refuted the DPP-hazard theory; cycle-fitting R19/R21 shows v_fmac_f32_dpp ~ 6cyc
// (3x plain v_fma). So phase 2 returns to LDS s-broadcast + plain FMA (full rate), with
// the two taxes that killed R15/R16 removed:
//  (1) AGPR parking of P: 16 named f4 fragments pinned to ARCH VGPRs by a zero-cost
//      empty asm "+v" constraint INSIDE the loop (parking would cost 32 copies/iter,
//      so the allocator keeps them in v-regs).
//  (2) LDS footprint: the s-exchange slot ALIASES the sample's dead A-region (group-
//      private after phase 1) — block stays 16.9KB -> 9 blocks/CU.
__global__ void __launch_bounds__(128)
admm_fused_kernel(const float* __restrict__ Ag, const float* __restrict__ bg,
                  const float* __restrict__ cg, const float* __restrict__ lbg,
                  const float* __restrict__ ubg, float* __restrict__ outg)
{
    __shared__ __align__(16) float A_lds[SPA * AS * 4];   // 16896 B (only LDS)

    const int t = threadIdx.x;

    // ---- stage A for the block's 8 samples (coalesced, xor-swizzled f4)
    {
        const float4* src = reinterpret_cast<const float4*>(Ag) +
                            (size_t)blockIdx.x * (SPA * MD * ND / 4);
        float4* dst = reinterpret_cast<float4*>(A_lds);
        #pragma unroll
        for (int r = 0; r < 8; ++r) {               // 1024 f4 / 128 threads
            int idx = r * 128 + t;
            int smp = idx >> 7;
            int row = (idx >> 3) & 15;
            int j   = idx & 7;
            dst[smp * AS + row * 8 + (j ^ (row & 7))] = src[idx];
        }
    }
    __syncthreads();   // only barrier

    const int lane = t & 63;
    const int l    = lane & 15;
    const int n0   = 2 * l;
    const int smp  = (t >> 6) * 4 + (lane >> 4);
    const size_t gs = (size_t)blockIdx.x * SPA + smp;
    const float* As = &A_lds[smp * AS * 4];

    // ---- own A row into registers
    f16v Ar0, Ar1;
    sfor<4>([&](auto J) {
        constexpr int j = decltype(J)::v;
        float4 v  = lds_a4(As, l, j);
        Ar0[4*j+0] = v.x;  Ar0[4*j+1] = v.y;  Ar0[4*j+2] = v.z;  Ar0[4*j+3] = v.w;
        float4 w4 = lds_a4(As, l, j + 4);
        Ar1[4*j+0] = w4.x; Ar1[4*j+1] = w4.y; Ar1[4*j+2] = w4.z; Ar1[4*j+3] = w4.w;
    });

    // ---- M = A A^T + jitter*I (row l)
    f16v Mrow, Vrow;
    sfor<16>([&](auto K) {
        constexpr int k = decltype(K)::v;
        float a0 = 0.f, a1 = 0.f, a2 = 0.f, a3 = 0.f;
        sfor<4>([&](auto J) {
            constexpr int j = decltype(J)::v;
            float4 v  = lds_a4(As, k, j);
            a0 += Ar0[4*j+0]*v.x;  a1 += Ar0[4*j+1]*v.y;
            a2 += Ar0[4*j+2]*v.z;  a3 += Ar0[4*j+3]*v.w;
            float4 w4 = lds_a4(As, k, j + 4);
            a0 += Ar1[4*j+0]*w4.x; a1 += Ar1[4*j+1]*w4.y;
            a2 += Ar1[4*j+2]*w4.z; a3 += Ar1[4*j+3]*w4.w;
        });
        Mrow[k] = (a0+a1)+(a2+a3) + ((k == l) ? kJitter : 0.f);
        Vrow[k] = (k == l) ? 1.f : 0.f;
    });

    // ---- triangular Gauss-Jordan inverse (SPD), width-16 shuffles
    sfor<16>([&](auto K) {
        constexpr int k = decltype(K)::v;
        float ip = 1.f / __shfl(Mrow[k], k, 16);
        float f  = (l == k) ? 0.f : Mrow[k] * ip;
        sfor<16>([&](auto J) {
            constexpr int j = decltype(J)::v;
            if constexpr (j > k) {
                float mj = __shfl(Mrow[j], k, 16);
                Mrow[j] = (l == k) ? mj * ip : Mrow[j] - f * mj;
            }
        });
        sfor<16>([&](auto J) {
            constexpr int j = decltype(J)::v;
            if constexpr (j < k) {
                float vj = __shfl(Vrow[j], k, 16);
                Vrow[j] = (l == k) ? vj * ip : Vrow[j] - f * vj;
            }
        });
        Vrow[k] = (l == k) ? ip : -f;
    });

    // ---- w = Minv b
    float w = 0.f;
    {
        float bval = bg[gs * MD + l];
        sfor<16>([&](auto K) {
            constexpr int k = decltype(K)::v;
            w += Vrow[k] * __shfl(bval, k, 16);
        });
    }

    // ---- C rows n0,n0+1 of A^T Minv via Vrow shuffles, fused with q = A^T w (R19-proven)
    f16v Ca = (f16v)0.0f, Cb = (f16v)0.0f;
    float q0 = 0.f, q1 = 0.f;
    sfor<16>([&](auto K) {
        constexpr int k = decltype(K)::v;
        f2 ak = lds_a2(As, k, n0);
        float wm = __shfl(w, k, 16);
        q0 = fmaf(ak[0], wm, q0);
        q1 = fmaf(ak[1], wm, q1);
        sfor<16>([&](auto M) {
            constexpr int m = decltype(M)::v;
            float mv = __shfl(Vrow[m], k, 16);   // Minv[k][m]
            Ca[m] = fmaf(ak[0], mv, Ca[m]);
            Cb[m] = fmaf(ak[1], mv, Cb[m]);
        });
    });

    // ---- P rows n0,n0+1 = (I - C A)/sigma into 16 NAMED f4 fragments
    // pa_k = P[n0][4k..4k+3], pb_k = P[n0+1][4k..4k+3]
    f4 pa0=(f4)0.f, pa1=(f4)0.f, pa2=(f4)0.f, pa3=(f4)0.f,
       pa4=(f4)0.f, pa5=(f4)0.f, pa6=(f4)0.f, pa7=(f4)0.f;
    f4 pb0=(f4)0.f, pb1=(f4)0.f, pb2=(f4)0.f, pb3=(f4)0.f,
       pb4=(f4)0.f, pb5=(f4)0.f, pb6=(f4)0.f, pb7=(f4)0.f;
#define ACC4(P, c, v) \
    P[0]=fmaf((c),(v).x,P[0]); P[1]=fmaf((c),(v).y,P[1]); \
    P[2]=fmaf((c),(v).z,P[2]); P[3]=fmaf((c),(v).w,P[3]);
    sfor<16>([&](auto M) {
        constexpr int m = decltype(M)::v;
        float c0 = Ca[m], c1 = Cb[m];
        float4 v;
        v = lds_a4(As, m, 0); ACC4(pa0, c0, v) ACC4(pb0, c1, v)
        v = lds_a4(As, m, 1); ACC4(pa1, c0, v) ACC4(pb1, c1, v)
        v = lds_a4(As, m, 2); ACC4(pa2, c0, v) ACC4(pb2, c1, v)
        v = lds_a4(As, m, 3); ACC4(pa3, c0, v) ACC4(pb3, c1, v)
        v = lds_a4(As, m, 4); ACC4(pa4, c0, v) ACC4(pb4, c1, v)
        v = lds_a4(As, m, 5); ACC4(pa5, c0, v) ACC4(pb5, c1, v)
        v = lds_a4(As, m, 6); ACC4(pa6, c0, v) ACC4(pb6, c1, v)
        v = lds_a4(As, m, 7); ACC4(pa7, c0, v) ACC4(pb7, c1, v)
    });
#undef ACC4
    constexpr float is = 1.f / kSigma;
#define FIN4(P, B, R) \
    P[0] = ((((B)+0)==(R) ? 1.f : 0.f) - P[0]) * is; \
    P[1] = ((((B)+1)==(R) ? 1.f : 0.f) - P[1]) * is; \
    P[2] = ((((B)+2)==(R) ? 1.f : 0.f) - P[2]) * is; \
    P[3] = ((((B)+3)==(R) ? 1.f : 0.f) - P[3]) * is;
    FIN4(pa0, 0,  n0) FIN4(pa1, 4,  n0) FIN4(pa2, 8,  n0) FIN4(pa3, 12, n0)
    FIN4(pa4, 16, n0) FIN4(pa5, 20, n0) FIN4(pa6, 24, n0) FIN4(pa7, 28, n0)
    FIN4(pb0, 0,  n0+1) FIN4(pb1, 4,  n0+1) FIN4(pb2, 8,  n0+1) FIN4(pb3, 12, n0+1)
    FIN4(pb4, 16, n0+1) FIN4(pb5, 20, n0+1) FIN4(pb6, 24, n0+1) FIN4(pb7, 28, n0+1)
#undef FIN4

    // ---- d = q - P c (one-time shuffles)
    float d0, d1;
    {
        float cv0 = cg[gs * ND + l];
        float cv1 = cg[gs * ND + 16 + l];
        float pc0 = 0.f, pc1 = 0.f;
#define DP4(PA, PB, CS, NB) { \
        float c_; \
        c_ = __shfl((CS), (NB)+0, 16); pc0 = fmaf(PA[0], c_, pc0); pc1 = fmaf(PB[0], c_, pc1); \
        c_ = __shfl((CS), (NB)+1, 16); pc0 = fmaf(PA[1], c_, pc0); pc1 = fmaf(PB[1], c_, pc1); \
        c_ = __shfl((CS), (NB)+2, 16); pc0 = fmaf(PA[2], c_, pc0); pc1 = fmaf(PB[2], c_, pc1); \
        c_ = __shfl((CS), (NB)+3, 16); pc0 = fmaf(PA[3], c_, pc0); pc1 = fmaf(PB[3], c_, pc1); }
        DP4(pa0, pb0, cv0, 0)  DP4(pa1, pb1, cv0, 4)
        DP4(pa2, pb2, cv0, 8)  DP4(pa3, pb3, cv0, 12)
        DP4(pa4, pb4, cv1, 0)  DP4(pa5, pb5, cv1, 4)
        DP4(pa6, pb6, cv1, 8)  DP4(pa7, pb7, cv1, 12)
#undef DP4
        d0 = q0 - pc0;
        d1 = q1 - pc1;
    }

    // ================= Phase 2: 100 iterations, s-exchange in the DEAD A-region =================
    // Slot = this sample's A region (group-private, dead after phase 1). f2 writes
    // cover all 32 banks once per group; uniform b128 reads are broadcast (2-way max).
    f2 lbv = *reinterpret_cast<const f2*>(lbg + gs * ND + n0);
    f2 ubv = *reinterpret_cast<const f2*>(ubg + gs * ND + n0);
    float lb0 = lbv[0], lb1 = lbv[1], ub0 = ubv[0], ub1 = ubv[1];
    float z0 = fminf(fmaxf(0.f, lb0), ub0);
    float z1 = fminf(fmaxf(0.f, lb1), ub1);
    float u0 = 0.f, u1 = 0.f, x0 = 0.f, x1 = 0.f;

    float* Sb = const_cast<float*>(As);
    const f4* Sv = reinterpret_cast<const f4*>(Sb);

    for (int it = 0; it < kIters; ++it) {
        // Pin the 16 P fragments to ARCH VGPRs (zero-instruction constraint: parking
        // them in AGPRs would cost 32 accvgpr copies/iter, so allocator keeps them in v).
        asm volatile("" : "+v"(pa0), "+v"(pa1), "+v"(pa2), "+v"(pa3),
                          "+v"(pa4), "+v"(pa5), "+v"(pa6), "+v"(pa7),
                          "+v"(pb0), "+v"(pb1), "+v"(pb2), "+v"(pb3),
                          "+v"(pb4), "+v"(pb5), "+v"(pb6), "+v"(pb7));
        f2 sp; sp[0] = z0 - u0; sp[1] = z1 - u1;           // rho == 1
        *reinterpret_cast<f2*>(&Sb[2 * l]) = sp;
        asm volatile("s_waitcnt lgkmcnt(0)" ::: "memory"); // wave-synchronous exchange
        f4 s0 = Sv[0], s1 = Sv[1], s2 = Sv[2], s3 = Sv[3];
        f4 s4 = Sv[4], s5 = Sv[5], s6 = Sv[6], s7 = Sv[7];
        float a0 = d0, a1 = 0.f, a2 = 0.f, a3 = 0.f;       // x0 chains (per component)
        float e0 = d1, e1 = 0.f, e2 = 0.f, e3 = 0.f;       // x1 chains
#define XK(PA, PB, S) \
        a0 = fmaf(PA[0], S[0], a0); a1 = fmaf(PA[1], S[1], a1); \
        a2 = fmaf(PA[2], S[2], a2); a3 = fmaf(PA[3], S[3], a3); \
        e0 = fmaf(PB[0], S[0], e0); e1 = fmaf(PB[1], S[1], e1); \
        e2 = fmaf(PB[2], S[2], e2); e3 = fmaf(PB[3], S[3], e3);
        XK(pa0, pb0, s0) XK(pa1, pb1, s1) XK(pa2, pb2, s2) XK(pa3, pb3, s3)
        XK(pa4, pb4, s4) XK(pa5, pb5, s5) XK(pa6, pb6, s6) XK(pa7, pb7, s7)
#undef XK
        x0 = (a0 + a1) + (a2 + a3);
        x1 = (e0 + e1) + (e2 + e3);
        float t0 = x0 + u0, t1 = x1 + u1;
        z0 = fminf(fmaxf(t0, lb0), ub0);
        z1 = fminf(fmaxf(t1, lb1), ub1);
        u0 = t0 - z0;
        u1 = t1 - z1;
    }

    f2 xo; xo[0] = x0; xo[1] = x1;
    *reinterpret_cast<f2*>(outg + gs * ND + n0) = xo;
}

extern "C" void kernel_launch(void* const* d_in, const int* in_sizes, int n_in,
                              void* d_out, int out_size, void* d_ws, size_t ws_size,
                              hipStream_t stream) {
    const float* A  = (const float*)d_in[0];
    const float* b  = (const float*)d_in[1];
    const float* c  = (const float*)d_in[2];
    const float* lb = (const float*)d_in[3];
    const float* ub = (const float*)d_in[4];
    float* out = (float*)d_out;
    const int B = in_sizes[1] / MD;      // 32768 samples
    admm_fused_kernel<<<B / SPA, 128, 0, stream>>>(A, b, c, lb, ub, out);
}

// Round 24
// 172.733 us; speedup vs baseline: 2.7393x; 2.7393x over previous
//
#include <hip/hip_runtime.h>

typedef float f16v __attribute__((ext_vector_type(16)));
typedef float f4 __attribute__((ext_vector_type(4)));
typedef float f2 __attribute__((ext_vector_type(2)));

// static_for with FRONTEND-constant indices (SSA, no alloca) — see R6 notes.
// R20 lesson: inline-asm referencing locals must be at FUNCTION SCOPE (not in lambdas).
template<int I> struct ic { static constexpr int v = I; };
template<int... I> struct iseq {};
template<int N, int... I> struct mk : mk<N-1, N-1, I...> {};
template<int... I> struct mk<0, I...> { using t = iseq<I...>; };
template<class F, int... I>
__device__ __forceinline__ void sfor_impl(F f, iseq<I...>) { (f(ic<I>{}), ...); }
template<int N, class F>
__device__ __forceinline__ void sfor(F f) { sfor_impl(f, typename mk<N>::t{}); }

namespace {
constexpr float kSigma  = 1.2f;    // 2*l2_reg + rho
constexpr float kJitter = 1e-5f;
constexpr int   kIters  = 100;
constexpr int   MD = 16;
constexpr int   ND = 32;
constexpr int   SPA = 8;     // samples per 128-thread block (16 lanes each)
constexpr int   AS  = 132;   // A sample stride in float4
}

__device__ __forceinline__ float4 lds_a4(const float* As, int r, int j) {
    return *reinterpret_cast<const float4*>(&As[r * 32 + ((j ^ (r & 7)) << 2)]);
}
__device__ __forceinline__ f2 lds_a2(const float* As, int r, int n) {
    return *reinterpret_cast<const f2*>(
        &As[r * 32 + ((((n >> 2) ^ (r & 7)) << 2) | (n & 3))]);
}

// ====== Fused kernel: R19 phase-1 (proven) + HYBRID phase-2 (DPP slots 1-7, LDS slots 8-15) ======
// Cycle-fits of R18/R19/R21/R22 show v_fmac_f32_dpp ~ 6cyc (3x plain v_fma): the pure
// DPP ring (R19, 155us) is DPP-RATE-bound. Hybrid splits the s-broadcast: rotations
// 1..7 stay on the DPP pipe (28 ops), rotations 8..15 become 8 loop-invariant-addressed
// ds_read_b64 window reads (lane l reads pairs of lanes (l+1)&15..(l+8)&15; 16 lanes
// cover all 32 banks once per group) + 32 full-rate v_fmac_f32. s-buffer aliases the
// sample's dead A-region (A unused in phase 2) — zero extra LDS, 9 blocks/CU kept.
// Per-iter VALU: 28*6 + 36*2 + tail ~ 290cyc vs R19's ~430.
__global__ void __launch_bounds__(128)
admm_fused_kernel(const float* __restrict__ Ag, const float* __restrict__ bg,
                  const float* __restrict__ cg, const float* __restrict__ lbg,
                  const float* __restrict__ ubg, float* __restrict__ outg)
{
    __shared__ __align__(16) float A_lds[SPA * AS * 4];   // 16896 B (only LDS)

    const int t = threadIdx.x;

    // ---- stage A for the block's 8 samples (coalesced, xor-swizzled f4)
    {
        const float4* src = reinterpret_cast<const float4*>(Ag) +
                            (size_t)blockIdx.x * (SPA * MD * ND / 4);
        float4* dst = reinterpret_cast<float4*>(A_lds);
        #pragma unroll
        for (int r = 0; r < 8; ++r) {
            int idx = r * 128 + t;
            int smp = idx >> 7;
            int row = (idx >> 3) & 15;
            int j   = idx & 7;
            dst[smp * AS + row * 8 + (j ^ (row & 7))] = src[idx];
        }
    }
    __syncthreads();   // only barrier in the kernel

    const int lane = t & 63;
    const int l    = lane & 15;
    const int n0   = 2 * l;
    const int smp  = (t >> 6) * 4 + (lane >> 4);
    const size_t gs = (size_t)blockIdx.x * SPA + smp;
    const float* As = &A_lds[smp * AS * 4];

    // ---- own A row into registers
    f16v Ar0, Ar1;
    sfor<4>([&](auto J) {
        constexpr int j = decltype(J)::v;
        float4 v  = lds_a4(As, l, j);
        Ar0[4*j+0] = v.x;  Ar0[4*j+1] = v.y;  Ar0[4*j+2] = v.z;  Ar0[4*j+3] = v.w;
        float4 w4 = lds_a4(As, l, j + 4);
        Ar1[4*j+0] = w4.x; Ar1[4*j+1] = w4.y; Ar1[4*j+2] = w4.z; Ar1[4*j+3] = w4.w;
    });

    // ---- M = A A^T + jitter*I (row l)
    f16v Mrow, Vrow;
    sfor<16>([&](auto K) {
        constexpr int k = decltype(K)::v;
        float a0 = 0.f, a1 = 0.f, a2 = 0.f, a3 = 0.f;
        sfor<4>([&](auto J) {
            constexpr int j = decltype(J)::v;
            float4 v  = lds_a4(As, k, j);
            a0 += Ar0[4*j+0]*v.x;  a1 += Ar0[4*j+1]*v.y;
            a2 += Ar0[4*j+2]*v.z;  a3 += Ar0[4*j+3]*v.w;
            float4 w4 = lds_a4(As, k, j + 4);
            a0 += Ar1[4*j+0]*w4.x; a1 += Ar1[4*j+1]*w4.y;
            a2 += Ar1[4*j+2]*w4.z; a3 += Ar1[4*j+3]*w4.w;
        });
        Mrow[k] = (a0+a1)+(a2+a3) + ((k == l) ? kJitter : 0.f);
        Vrow[k] = (k == l) ? 1.f : 0.f;
    });

    // ---- triangular Gauss-Jordan inverse (SPD), width-16 shuffles
    sfor<16>([&](auto K) {
        constexpr int k = decltype(K)::v;
        float ip = 1.f / __shfl(Mrow[k], k, 16);
        float f  = (l == k) ? 0.f : Mrow[k] * ip;
        sfor<16>([&](auto J) {
            constexpr int j = decltype(J)::v;
            if constexpr (j > k) {
                float mj = __shfl(Mrow[j], k, 16);
                Mrow[j] = (l == k) ? mj * ip : Mrow[j] - f * mj;
            }
        });
        sfor<16>([&](auto J) {
            constexpr int j = decltype(J)::v;
            if constexpr (j < k) {
                float vj = __shfl(Vrow[j], k, 16);
                Vrow[j] = (l == k) ? vj * ip : Vrow[j] - f * vj;
            }
        });
        Vrow[k] = (l == k) ? ip : -f;
    });

    // ---- w = Minv b
    float w = 0.f;
    {
        float bval = bg[gs * MD + l];
        sfor<16>([&](auto K) {
            constexpr int k = decltype(K)::v;
            w += Vrow[k] * __shfl(bval, k, 16);
        });
    }

    // ---- C rows n0,n0+1 of A^T Minv via Vrow shuffles, fused with q = A^T w
    f16v Ca = (f16v)0.0f, Cb = (f16v)0.0f;
    float q0 = 0.f, q1 = 0.f;
    sfor<16>([&](auto K) {
        constexpr int k = decltype(K)::v;
        f2 ak = lds_a2(As, k, n0);
        float wm = __shfl(w, k, 16);
        q0 = fmaf(ak[0], wm, q0);
        q1 = fmaf(ak[1], wm, q1);
        sfor<16>([&](auto M) {
            constexpr int m = decltype(M)::v;
            float mv = __shfl(Vrow[m], k, 16);   // Minv[k][m]
            Ca[m] = fmaf(ak[0], mv, Ca[m]);
            Cb[m] = fmaf(ak[1], mv, Cb[m]);
        });
    });

    // ---- P in RING order: Qa_j = (P[2l][2cp], P[2l][2cp+1]), Qb_j = row 2l+1; cp=(l-j)&15.
    // Identity (col==2l / 2l+1) lands only in slot 0.
    constexpr float is = 1.f / kSigma;
#define QBUILD(j)                                                             \
    f2 Qa##j, Qb##j;                                                          \
    {                                                                         \
        const int n = 2 * ((l - (j)) & 15);                                   \
        float qa0 = 0.f, qa1 = 0.f, qb0 = 0.f, qb1 = 0.f;                     \
        sfor<16>([&](auto M) {                                                \
            constexpr int m = decltype(M)::v;                                 \
            f2 ak = lds_a2(As, m, n);                                         \
            qa0 = fmaf(Ca[m], ak[0], qa0); qa1 = fmaf(Ca[m], ak[1], qa1);     \
            qb0 = fmaf(Cb[m], ak[0], qb0); qb1 = fmaf(Cb[m], ak[1], qb1);     \
        });                                                                   \
        Qa##j[0] = ((((j) == 0) ? 1.f : 0.f) - qa0) * is;                     \
        Qa##j[1] = (0.f - qa1) * is;                                          \
        Qb##j[0] = (0.f - qb0) * is;                                          \
        Qb##j[1] = ((((j) == 0) ? 1.f : 0.f) - qb1) * is;                     \
    }
    QBUILD(0)  QBUILD(1)  QBUILD(2)  QBUILD(3)
    QBUILD(4)  QBUILD(5)  QBUILD(6)  QBUILD(7)
    QBUILD(8)  QBUILD(9)  QBUILD(10) QBUILD(11)
    QBUILD(12) QBUILD(13) QBUILD(14) QBUILD(15)
#undef QBUILD

    // ---- d = q - P c (ring order; one-time shuffles)
    float d0, d1;
    {
        f2 cpr = *reinterpret_cast<const f2*>(cg + gs * ND + n0);
        float pc0 = 0.f, pc1 = 0.f;
#define DSTEP(j) {                                                            \
        const int cp = (l - (j)) & 15;                                        \
        float c0 = __shfl(cpr[0], cp, 16);                                    \
        float c1 = __shfl(cpr[1], cp, 16);                                    \
        pc0 += Qa##j[0]*c0 + Qa##j[1]*c1;                                     \
        pc1 += Qb##j[0]*c0 + Qb##j[1]*c1; }
        DSTEP(0)  DSTEP(1)  DSTEP(2)  DSTEP(3)
        DSTEP(4)  DSTEP(5)  DSTEP(6)  DSTEP(7)
        DSTEP(8)  DSTEP(9)  DSTEP(10) DSTEP(11)
        DSTEP(12) DSTEP(13) DSTEP(14) DSTEP(15)
#undef DSTEP
        d0 = q0 - pc0;
        d1 = q1 - pc1;
    }

    // ================= Phase 2: hybrid DPP + LDS-window iterations =================
    f2 lbv = *reinterpret_cast<const f2*>(lbg + gs * ND + n0);
    f2 ubv = *reinterpret_cast<const f2*>(ubg + gs * ND + n0);
    float lb0 = lbv[0], lb1 = lbv[1], ub0 = ubv[0], ub1 = ubv[1];
    float z0 = fminf(fmaxf(0.f, lb0), ub0);
    float z1 = fminf(fmaxf(0.f, lb1), ub1);
    float u0 = 0.f, u1 = 0.f, x0 = 0.f, x1 = 0.f;

    // s-buffer aliases the (dead) A region of this sample. Loop-invariant window
    // addresses: slot j (8..15) needs the pair of lane cp=(l-j)&15=(l+16-j)&15.
    float* Sb = const_cast<float*>(As);
    const f2* W8  = reinterpret_cast<const f2*>(&Sb[2 * ((l + 8) & 15)]);
    const f2* W9  = reinterpret_cast<const f2*>(&Sb[2 * ((l + 7) & 15)]);
    const f2* W10 = reinterpret_cast<const f2*>(&Sb[2 * ((l + 6) & 15)]);
    const f2* W11 = reinterpret_cast<const f2*>(&Sb[2 * ((l + 5) & 15)]);
    const f2* W12 = reinterpret_cast<const f2*>(&Sb[2 * ((l + 4) & 15)]);
    const f2* W13 = reinterpret_cast<const f2*>(&Sb[2 * ((l + 3) & 15)]);
    const f2* W14 = reinterpret_cast<const f2*>(&Sb[2 * ((l + 2) & 15)]);
    const f2* W15 = reinterpret_cast<const f2*>(&Sb[2 * ((l + 1) & 15)]);

    // DPP slot (rotation fused into FMA); src rotated, multiplied by ring-ordered Q.
#define FSTEP(j)                                                              \
    asm("v_fmac_f32_dpp %0, %1, %2 row_ror:" #j " row_mask:0xf bank_mask:0xf" \
        : "+v"(ae) : "v"(s0), "v"(Qa##j[0]));                                 \
    asm("v_fmac_f32_dpp %0, %1, %2 row_ror:" #j " row_mask:0xf bank_mask:0xf" \
        : "+v"(ao) : "v"(s1), "v"(Qa##j[1]));                                 \
    asm("v_fmac_f32_dpp %0, %1, %2 row_ror:" #j " row_mask:0xf bank_mask:0xf" \
        : "+v"(be) : "v"(s0), "v"(Qb##j[0]));                                 \
    asm("v_fmac_f32_dpp %0, %1, %2 row_ror:" #j " row_mask:0xf bank_mask:0xf" \
        : "+v"(bo) : "v"(s1), "v"(Qb##j[1]));
    // LDS slot: windowed pair + full-rate fmac ("v" keeps Q in arch VGPRs, as R19).
#define LSTEP(j, Wj) {                                                        \
        f2 r = *(Wj);                                                         \
        asm("v_fmac_f32 %0, %1, %2" : "+v"(ae) : "v"(Qa##j[0]), "v"(r[0]));   \
        asm("v_fmac_f32 %0, %1, %2" : "+v"(ao) : "v"(Qa##j[1]), "v"(r[1]));   \
        asm("v_fmac_f32 %0, %1, %2" : "+v"(be) : "v"(Qb##j[0]), "v"(r[0]));   \
        asm("v_fmac_f32 %0, %1, %2" : "+v"(bo) : "v"(Qb##j[1]), "v"(r[1])); }

    for (int it = 0; it < kIters; ++it) {
        float s0 = z0 - u0, s1 = z1 - u1;          // own column pair (rho == 1)
        f2 sp; sp[0] = s0; sp[1] = s1;
        *reinterpret_cast<f2*>(&Sb[2 * l]) = sp;
        asm volatile("s_waitcnt lgkmcnt(0)" ::: "memory");  // wave-synchronous
        float ae = d0, ao = 0.f, be = d1, bo = 0.f;
        // slot 0: local
        ae = fmaf(Qa0[0], s0, ae); ao = fmaf(Qa0[1], s1, ao);
        be = fmaf(Qb0[0], s0, be); bo = fmaf(Qb0[1], s1, bo);
        // slots 1..7: DPP pipe
        FSTEP(1)  FSTEP(2)  FSTEP(3)  FSTEP(4)  FSTEP(5)  FSTEP(6)  FSTEP(7)
        // slots 8..15: LDS window + full-rate FMA
        LSTEP(8,  W8)  LSTEP(9,  W9)  LSTEP(10, W10) LSTEP(11, W11)
        LSTEP(12, W12) LSTEP(13, W13) LSTEP(14, W14) LSTEP(15, W15)
        x0 = ae + ao;
        x1 = be + bo;
        float t0 = x0 + u0, t1 = x1 + u1;
        z0 = fminf(fmaxf(t0, lb0), ub0);
        z1 = fminf(fmaxf(t1, lb1), ub1);
        u0 = t0 - z0;
        u1 = t1 - z1;
    }
#undef FSTEP
#undef LSTEP

    f2 xo; xo[0] = x0; xo[1] = x1;
    *reinterpret_cast<f2*>(outg + gs * ND + n0) = xo;
}

extern "C" void kernel_launch(void* const* d_in, const int* in_sizes, int n_in,
                              void* d_out, int out_size, void* d_ws, size_t ws_size,
                              hipStream_t stream) {
    const float* A  = (const float*)d_in[0];
    const float* b  = (const float*)d_in[1];
    const float* c  = (const float*)d_in[2];
    const float* lb = (const float*)d_in[3];
    const float* ub = (const float*)d_in[4];
    float* out = (float*)d_out;
    const int B = in_sizes[1] / MD;      // 32768 samples
    admm_fused_kernel<<<B / SPA, 128, 0, stream>>>(A, b, c, lb, ub, out);
}